// Round 7
// baseline (845.752 us; speedup 1.0000x reference)
//
#include <hip/hip_runtime.h>
#include <hip/hip_bf16.h>

#define CIN 512
#define COUT 512
#define BATCH 16
#define NP 3844          // 62*62 output positions
#define OW 62

#define W_MUL_DENSE 0.044194173824159216f
#define W_MUL_CONV  0.014731391274719736f

using short8  = __attribute__((ext_vector_type(8))) short;
using floatx4 = __attribute__((ext_vector_type(4))) float;
using uintx4  = __attribute__((ext_vector_type(4))) unsigned int;

__device__ __forceinline__ unsigned short f2bfu(float f) {
    unsigned u = __builtin_bit_cast(unsigned, f);
    u += 0x7FFFu + ((u >> 16) & 1u);   // round-to-nearest-even
    return (unsigned short)(u >> 16);
}

// ---------------- prep kernels ----------------

__global__ void emc_style_kernel(const float* __restrict__ y, const float* __restrict__ dw,
                                 const float* __restrict__ db, float* __restrict__ s) {
    int idx = blockIdx.x * 256 + threadIdx.x;       // 16*512
    int b = idx >> 9, c = idx & 511;
    const float4* yb = (const float4*)(y + b * 512);
    const float4* wc = (const float4*)(dw + c * 512);
    float acc = 0.f;
#pragma unroll 4
    for (int l = 0; l < 128; ++l) {
        float4 a = yb[l], w4 = wc[l];
        acc += a.x * w4.x + a.y * w4.y + a.z * w4.z + a.w * w4.w;
    }
    s[idx] = acc * W_MUL_DENSE + db[c];
}

__global__ void emc_wsq_kernel(const float* __restrict__ w, float* __restrict__ wsq) {
    int idx = blockIdx.x * 256 + threadIdx.x;       // 512*512
    const float* p = w + (size_t)idx * 9;
    float a = 0.f;
#pragma unroll
    for (int j = 0; j < 9; ++j) a += p[j] * p[j];
    wsq[idx] = a;
}

__global__ void emc_demod_kernel(const float* __restrict__ s, const float* __restrict__ wsq,
                                 float* __restrict__ d) {
    int idx = blockIdx.x * 256 + threadIdx.x;       // 16*512
    int b = idx >> 9, o = idx & 511;
    const float4* sb = (const float4*)(s + b * 512);
    const float4* wo = (const float4*)(wsq + o * 512);
    float acc = 0.f;
#pragma unroll 4
    for (int l = 0; l < 128; ++l) {
        float4 a = sb[l], c = wo[l];
        acc += a.x * a.x * c.x + a.y * a.y * c.y + a.z * a.z * c.z + a.w * a.w * c.w;
    }
    d[idx] = rsqrtf(W_MUL_CONV * W_MUL_CONV * acc + 1e-8f);
}

// wb[(o*9+kpos)*512 + i] = bf16(w[(o*512+i)*9 + kpos])
__global__ void emc_wrepack_kernel(const float* __restrict__ w, unsigned short* __restrict__ wb) {
    int idx = blockIdx.x * 256 + threadIdx.x;       // 512*9*512
    int i = idx & 511;
    int r = idx >> 9;
    int kpos = r % 9;
    int o = r / 9;
    wb[idx] = f2bfu(w[(size_t)(o * 512 + i) * 9 + kpos]);
}

// ---------------- main conv kernel ----------------
// 512 threads = 8 waves; wave (wr = wid>>1, wc = wid&1) owns a 64o x 64p tile of
// the 256o x 128p block tile -> acc = 4x4 floatx4 = 64 regs/lane. Target total
// <=128 regs -> 4 waves/SIMD (16 waves/CU), double previous occupancy.
// A (weights): per-wave global->register (4 x dwordx4/phase), single fA set
//   issued one phase ahead right after last use; stall hidden by TLP.
// B (x-halo): [4 rows][64 cols][32 i] bf16, 80B granules in LDS, staged once per
//   i-tile; 2 owner-threads per granule (16 i each). Split load/convert (T14).
// No per-phase barriers; 2 barriers per i-tile (B handoff).

__global__ __launch_bounds__(512, 4) void emc_conv_kernel(
    const float* __restrict__ x, const unsigned short* __restrict__ wb,
    const float* __restrict__ sv, const float* __restrict__ dv,
    float* __restrict__ out) {

    __shared__ __align__(16) unsigned short smB[260 * 40];      // 20.8 KB
    __shared__ float s_s[512];
    __shared__ float s_d[256];

    // bijective XCD swizzle (gridDim = 992, 992 % 8 == 0)
    int orig = blockIdx.x;
    int cpx = gridDim.x >> 3;
    int bid = (orig & 7) * cpx + (orig >> 3);

    int b = bid / 62;               // 62 blocks per batch = 2 o-tiles * 31 strips
    int t = bid - b * 62;
    int ot = t & 1;
    int strip = t >> 1;
    int oB = ot * 256;
    int r0 = strip * 2;

    int tid = threadIdx.x;
    int lane = tid & 63;
    int wid = tid >> 6;

    s_s[tid & 511] = sv[b * 512 + (tid & 511)];
    if (tid < 256) s_d[tid] = dv[b * 512 + oB + tid];

    // ---- B staging ids: 2 owners per granule, owner h stages i in [16h,16h+16) ----
    int sc = tid & 63;
    int sr = (tid >> 6) & 3;
    int h  = tid >> 8;               // 0/1
    const float* xrow = x + (size_t)b * (512 * 4096) + (r0 + sr) * 64 + sc + (size_t)h * 16 * 4096;
    unsigned short* bg = smB + (sr * 64 + sc) * 40 + h * 16;

    // ---- compute ids ----
    int frc = lane & 15, q = lane >> 4;
    int wr = wid >> 1, wc = wid & 1;

    const char* wbB = (const char*)wb + (size_t)oB * 9216;
    int voffA[4];
#pragma unroll
    for (int m = 0; m < 4; ++m)
        voffA[m] = (wr * 64 + m * 16 + frc) * 9216 + q * 16;

    int bidx0 = (wc * 64 + frc) * 40 + q * 8;    // + n*640 shorts per n-frag

    floatx4 acc[4][4];
#pragma unroll
    for (int m = 0; m < 4; ++m)
#pragma unroll
        for (int n = 0; n < 4; ++n) acc[m][n] = floatx4{0.f, 0.f, 0.f, 0.f};

    short8 fA[4];
    float raw[4];        // 2-slot ring of 2 f32
    unsigned held[8];    // 16 i packed

    auto AISSUE = [&](int it, int kN) {
        const char* abase = wbB + (size_t)(kN * 512 + it * 32) * 2;
#pragma unroll
        for (int m = 0; m < 4; ++m)
            fA[m] = *(const short8*)(abase + voffA[m]);
    };

    auto LOAD_SLICE = [&](int itgt, int sl) {     // issue only: 2 f32
        const float* xp = xrow + ((size_t)itgt * 32 + sl * 2) * 4096;
        int r = (sl & 1) * 2;
        raw[r + 0] = xp[0];
        raw[r + 1] = xp[4096];
    };

    auto CONVERT = [&](int itgt, int sl) {        // one phase after its LOAD
        int i0 = itgt * 32 + h * 16 + sl * 2;
        int r = (sl & 1) * 2;
        float v0 = raw[r + 0] * s_s[i0];
        float v1 = raw[r + 1] * s_s[i0 + 1];
        held[sl] = (unsigned)f2bfu(v0) | ((unsigned)f2bfu(v1) << 16);
    };

    auto WRITE_B = [&]() {
        *(uintx4*)(bg)     = uintx4{held[0], held[1], held[2], held[3]};
        *(uintx4*)(bg + 8) = uintx4{held[4], held[5], held[6], held[7]};
    };

    auto MFMA16 = [&](int kpos) {
        int kh = kpos / 3, kw = kpos - kh * 3;
        int bo = (kh * 64 + kw) * 40;
        short8 bfr[4];
#pragma unroll
        for (int n = 0; n < 4; ++n) bfr[n] = *(const short8*)(smB + bidx0 + bo + n * 640);
        __builtin_amdgcn_s_setprio(1);
#pragma unroll
        for (int m = 0; m < 4; ++m)
#pragma unroll
            for (int n = 0; n < 4; ++n)
                acc[m][n] = __builtin_amdgcn_mfma_f32_16x16x32_bf16(
                    fA[m], bfr[n], acc[m][n], 0, 0, 0);
        __builtin_amdgcn_s_setprio(0);
    };

    __syncthreads();   // s_s / s_d ready

    // ---- prologue: A for phase 0; stage + convert + write B(i-tile 0) ----
    AISSUE(0, 0);
#pragma unroll
    for (int sl = 0; sl < 8; ++sl) {
        LOAD_SLICE(0, sl);
        if (sl > 0) CONVERT(0, sl - 1);
    }
    CONVERT(0, 7);
    WRITE_B();
    __syncthreads();

    // ---- main loop ----
    for (int itile = 0; itile < 15; ++itile) {
#pragma unroll
        for (int kpos = 0; kpos < 9; ++kpos) {
            if (kpos < 8) LOAD_SLICE(itile + 1, kpos);
            if (kpos >= 1) CONVERT(itile + 1, kpos - 1);
            MFMA16(kpos);
            if (kpos < 8) {
                AISSUE(itile, kpos + 1);       // A for next phase (after last use)
            } else {
                AISSUE(itile + 1, 0);
                __builtin_amdgcn_s_barrier();  // all waves done reading smB
                WRITE_B();
                asm volatile("s_waitcnt lgkmcnt(0)" ::: "memory");
                __builtin_amdgcn_s_barrier();  // new B visible
            }
        }
    }
    // peeled i-tile 15 (no staging)
#pragma unroll
    for (int kpos = 0; kpos < 9; ++kpos) {
        MFMA16(kpos);
        if (kpos < 8) AISSUE(15, kpos + 1);
    }

    // ---- epilogue: scale by WMC * d[b,o], store fp32 ----
    size_t outb = (size_t)b * 512 * NP;
#pragma unroll
    for (int m = 0; m < 4; ++m) {
#pragma unroll
        for (int r = 0; r < 4; ++r) {
            int o_l = wr * 64 + m * 16 + q * 4 + r;
            float scale = W_MUL_CONV * s_d[o_l];
            size_t rb = outb + (size_t)(oB + o_l) * NP + strip * 124 + wc * OW;
#pragma unroll
            for (int n = 0; n < 4; ++n) {
                int col = n * 16 + frc;
                if (col < OW) out[rb + col] = acc[m][n][r] * scale;
            }
        }
    }
}

// ---------------- launch ----------------
extern "C" void kernel_launch(void* const* d_in, const int* in_sizes, int n_in,
                              void* d_out, int out_size, void* d_ws, size_t ws_size,
                              hipStream_t stream) {
    const float* x  = (const float*)d_in[0];   // [16,512,64,64]
    const float* y  = (const float*)d_in[1];   // [16,512]
    const float* dw = (const float*)d_in[2];   // [512,512]
    const float* db = (const float*)d_in[3];   // [512]
    const float* w  = (const float*)d_in[4];   // [512,512,3,3]
    float* out = (float*)d_out;                // [16,512,62,62]

    char* ws = (char*)d_ws;
    float* s_  = (float*)ws;                               // 16*512 f32   (32 KB)
    float* d_  = (float*)(ws + 32768);                     // 16*512 f32   (32 KB)
    float* wsq = (float*)(ws + 65536);                     // 512*512 f32  (1 MB)
    unsigned short* wb = (unsigned short*)(ws + 65536 + 1048576);  // 512*9*512 bf16 (4.72 MB)

    emc_style_kernel<<<32, 256, 0, stream>>>(y, dw, db, s_);
    emc_wsq_kernel<<<1024, 256, 0, stream>>>(w, wsq);
    emc_demod_kernel<<<32, 256, 0, stream>>>(s_, wsq, d_);
    emc_wrepack_kernel<<<9216, 256, 0, stream>>>(w, wb);
    emc_conv_kernel<<<16 * 62, 512, 0, stream>>>(x, wb, s_, d_, out);
}

// Round 8
// 602.636 us; speedup vs baseline: 1.4034x; 1.4034x over previous
//
#include <hip/hip_runtime.h>
#include <hip/hip_bf16.h>

#define CIN 512
#define COUT 512
#define BATCH 16
#define NP 3844          // 62*62 output positions
#define OW 62

#define W_MUL_DENSE 0.044194173824159216f
#define W_MUL_CONV  0.014731391274719736f

using short8  = __attribute__((ext_vector_type(8))) short;
using floatx4 = __attribute__((ext_vector_type(4))) float;
using uintx4  = __attribute__((ext_vector_type(4))) unsigned int;

__device__ __forceinline__ unsigned short f2bfu(float f) {
    unsigned u = __builtin_bit_cast(unsigned, f);
    u += 0x7FFFu + ((u >> 16) & 1u);   // round-to-nearest-even
    return (unsigned short)(u >> 16);
}

// ---------------- prep kernels ----------------

__global__ void emc_style_kernel(const float* __restrict__ y, const float* __restrict__ dw,
                                 const float* __restrict__ db, float* __restrict__ s) {
    int idx = blockIdx.x * 256 + threadIdx.x;       // 16*512
    int b = idx >> 9, c = idx & 511;
    const float4* yb = (const float4*)(y + b * 512);
    const float4* wc = (const float4*)(dw + c * 512);
    float acc = 0.f;
#pragma unroll 4
    for (int l = 0; l < 128; ++l) {
        float4 a = yb[l], w4 = wc[l];
        acc += a.x * w4.x + a.y * w4.y + a.z * w4.z + a.w * w4.w;
    }
    s[idx] = acc * W_MUL_DENSE + db[c];
}

__global__ void emc_wsq_kernel(const float* __restrict__ w, float* __restrict__ wsq) {
    int idx = blockIdx.x * 256 + threadIdx.x;       // 512*512
    const float* p = w + (size_t)idx * 9;
    float a = 0.f;
#pragma unroll
    for (int j = 0; j < 9; ++j) a += p[j] * p[j];
    wsq[idx] = a;
}

__global__ void emc_demod_kernel(const float* __restrict__ s, const float* __restrict__ wsq,
                                 float* __restrict__ d) {
    int idx = blockIdx.x * 256 + threadIdx.x;       // 16*512
    int b = idx >> 9, o = idx & 511;
    const float4* sb = (const float4*)(s + b * 512);
    const float4* wo = (const float4*)(wsq + o * 512);
    float acc = 0.f;
#pragma unroll 4
    for (int l = 0; l < 128; ++l) {
        float4 a = sb[l], c = wo[l];
        acc += a.x * a.x * c.x + a.y * a.y * c.y + a.z * a.z * c.z + a.w * a.w * c.w;
    }
    d[idx] = rsqrtf(W_MUL_CONV * W_MUL_CONV * acc + 1e-8f);
}

// wb[(o*9+kpos)*512 + i] = bf16(w[(o*512+i)*9 + kpos])
__global__ void emc_wrepack_kernel(const float* __restrict__ w, unsigned short* __restrict__ wb) {
    int idx = blockIdx.x * 256 + threadIdx.x;       // 512*9*512
    int i = idx & 511;
    int r = idx >> 9;
    int kpos = r % 9;
    int o = r / 9;
    wb[idx] = f2bfu(w[(size_t)(o * 512 + i) * 9 + kpos]);
}

// ---------------- main conv kernel ----------------
// 512 threads = 8 waves; wave (wr = wid>>1, wc = wid&1) owns a 64o x 64p tile of
// the 256o x 128p block tile -> acc = 4x4 floatx4 = 64 regs/lane.
// __launch_bounds__(512, 2): 2 BLOCKS/CU (CUDA semantics of 2nd arg, confirmed
// empirically R7: (512,4) gave a 64-VGPR budget = 8 waves/SIMD and spilled) ->
// 16 waves/CU = 4 waves/SIMD at a 128-VGPR budget. Working set ~123 regs.
// A (weights): per-wave global->register (4 x dwordx4/phase), single fA set
//   issued one phase ahead right after last use; latency hidden by TLP.
// B (x-halo): [4 rows][64 cols][32 i] bf16, 80B granules in LDS, staged once per
//   i-tile; 2 owner-threads per granule (16 i each). Split load/convert (T14).
// No per-phase barriers; 2 barriers per i-tile (B handoff).

__global__ __launch_bounds__(512, 2) void emc_conv_kernel(
    const float* __restrict__ x, const unsigned short* __restrict__ wb,
    const float* __restrict__ sv, const float* __restrict__ dv,
    float* __restrict__ out) {

    __shared__ __align__(16) unsigned short smB[260 * 40];      // 20.8 KB
    __shared__ float s_s[512];
    __shared__ float s_d[256];

    // bijective XCD swizzle (gridDim = 992, 992 % 8 == 0)
    int orig = blockIdx.x;
    int cpx = gridDim.x >> 3;
    int bid = (orig & 7) * cpx + (orig >> 3);

    int b = bid / 62;               // 62 blocks per batch = 2 o-tiles * 31 strips
    int t = bid - b * 62;
    int ot = t & 1;
    int strip = t >> 1;
    int oB = ot * 256;
    int r0 = strip * 2;

    int tid = threadIdx.x;
    int lane = tid & 63;
    int wid = tid >> 6;

    s_s[tid & 511] = sv[b * 512 + (tid & 511)];
    if (tid < 256) s_d[tid] = dv[b * 512 + oB + tid];

    // ---- B staging ids: 2 owners per granule, owner h stages i in [16h,16h+16) ----
    int sc = tid & 63;
    int sr = (tid >> 6) & 3;
    int h  = tid >> 8;               // 0/1
    const float* xrow = x + (size_t)b * (512 * 4096) + (r0 + sr) * 64 + sc + (size_t)h * 16 * 4096;
    unsigned short* bg = smB + (sr * 64 + sc) * 40 + h * 16;

    // ---- compute ids ----
    int frc = lane & 15, q = lane >> 4;
    int wr = wid >> 1, wc = wid & 1;

    const char* wbB = (const char*)wb + (size_t)oB * 9216;
    int voffA[4];
#pragma unroll
    for (int m = 0; m < 4; ++m)
        voffA[m] = (wr * 64 + m * 16 + frc) * 9216 + q * 16;

    int bidx0 = (wc * 64 + frc) * 40 + q * 8;    // + n*640 shorts per n-frag

    floatx4 acc[4][4];
#pragma unroll
    for (int m = 0; m < 4; ++m)
#pragma unroll
        for (int n = 0; n < 4; ++n) acc[m][n] = floatx4{0.f, 0.f, 0.f, 0.f};

    short8 fA[4];
    float raw[4];        // 2-slot ring of 2 f32
    unsigned held[8];    // 16 i packed

    auto AISSUE = [&](int it, int kN) {
        const char* abase = wbB + (size_t)(kN * 512 + it * 32) * 2;
#pragma unroll
        for (int m = 0; m < 4; ++m)
            fA[m] = *(const short8*)(abase + voffA[m]);
    };

    auto LOAD_SLICE = [&](int itgt, int sl) {     // issue only: 2 f32
        const float* xp = xrow + ((size_t)itgt * 32 + sl * 2) * 4096;
        int r = (sl & 1) * 2;
        raw[r + 0] = xp[0];
        raw[r + 1] = xp[4096];
    };

    auto CONVERT = [&](int itgt, int sl) {        // one phase after its LOAD
        int i0 = itgt * 32 + h * 16 + sl * 2;
        int r = (sl & 1) * 2;
        float v0 = raw[r + 0] * s_s[i0];
        float v1 = raw[r + 1] * s_s[i0 + 1];
        held[sl] = (unsigned)f2bfu(v0) | ((unsigned)f2bfu(v1) << 16);
    };

    auto WRITE_B = [&]() {
        *(uintx4*)(bg)     = uintx4{held[0], held[1], held[2], held[3]};
        *(uintx4*)(bg + 8) = uintx4{held[4], held[5], held[6], held[7]};
    };

    auto MFMA16 = [&](int kpos) {
        int kh = kpos / 3, kw = kpos - kh * 3;
        int bo = (kh * 64 + kw) * 40;
        __builtin_amdgcn_s_setprio(1);
#pragma unroll
        for (int np = 0; np < 2; ++np) {         // two n-pairs: caps bfr at 2 live
            short8 bfr[2];
#pragma unroll
            for (int j = 0; j < 2; ++j)
                bfr[j] = *(const short8*)(smB + bidx0 + bo + (np * 2 + j) * 640);
#pragma unroll
            for (int m = 0; m < 4; ++m)
#pragma unroll
                for (int j = 0; j < 2; ++j)
                    acc[m][np * 2 + j] = __builtin_amdgcn_mfma_f32_16x16x32_bf16(
                        fA[m], bfr[j], acc[m][np * 2 + j], 0, 0, 0);
        }
        __builtin_amdgcn_s_setprio(0);
    };

    __syncthreads();   // s_s / s_d ready

    // ---- prologue: A for phase 0; stage + convert + write B(i-tile 0) ----
    AISSUE(0, 0);
#pragma unroll
    for (int sl = 0; sl < 8; ++sl) {
        LOAD_SLICE(0, sl);
        if (sl > 0) CONVERT(0, sl - 1);
    }
    CONVERT(0, 7);
    WRITE_B();
    __syncthreads();

    // ---- main loop ----
    for (int itile = 0; itile < 15; ++itile) {
#pragma unroll
        for (int kpos = 0; kpos < 9; ++kpos) {
            if (kpos < 8) LOAD_SLICE(itile + 1, kpos);
            if (kpos >= 1) CONVERT(itile + 1, kpos - 1);
            MFMA16(kpos);
            if (kpos < 8) {
                AISSUE(itile, kpos + 1);       // A for next phase (after last use)
            } else {
                AISSUE(itile + 1, 0);
                __builtin_amdgcn_s_barrier();  // all waves done reading smB
                WRITE_B();
                asm volatile("s_waitcnt lgkmcnt(0)" ::: "memory");
                __builtin_amdgcn_s_barrier();  // new B visible
            }
        }
    }
    // peeled i-tile 15 (no staging)
#pragma unroll
    for (int kpos = 0; kpos < 9; ++kpos) {
        MFMA16(kpos);
        if (kpos < 8) AISSUE(15, kpos + 1);
    }

    // ---- epilogue: scale by WMC * d[b,o], store fp32 ----
    size_t outb = (size_t)b * 512 * NP;
#pragma unroll
    for (int m = 0; m < 4; ++m) {
#pragma unroll
        for (int r = 0; r < 4; ++r) {
            int o_l = wr * 64 + m * 16 + q * 4 + r;
            float scale = W_MUL_CONV * s_d[o_l];
            size_t rb = outb + (size_t)(oB + o_l) * NP + strip * 124 + wc * OW;
#pragma unroll
            for (int n = 0; n < 4; ++n) {
                int col = n * 16 + frc;
                if (col < OW) out[rb + col] = acc[m][n][r] * scale;
            }
        }
    }
}

// ---------------- launch ----------------
extern "C" void kernel_launch(void* const* d_in, const int* in_sizes, int n_in,
                              void* d_out, int out_size, void* d_ws, size_t ws_size,
                              hipStream_t stream) {
    const float* x  = (const float*)d_in[0];   // [16,512,64,64]
    const float* y  = (const float*)d_in[1];   // [16,512]
    const float* dw = (const float*)d_in[2];   // [512,512]
    const float* db = (const float*)d_in[3];   // [512]
    const float* w  = (const float*)d_in[4];   // [512,512,3,3]
    float* out = (float*)d_out;                // [16,512,62,62]

    char* ws = (char*)d_ws;
    float* s_  = (float*)ws;                               // 16*512 f32   (32 KB)
    float* d_  = (float*)(ws + 32768);                     // 16*512 f32   (32 KB)
    float* wsq = (float*)(ws + 65536);                     // 512*512 f32  (1 MB)
    unsigned short* wb = (unsigned short*)(ws + 65536 + 1048576);  // 512*9*512 bf16 (4.72 MB)

    emc_style_kernel<<<32, 256, 0, stream>>>(y, dw, db, s_);
    emc_wsq_kernel<<<1024, 256, 0, stream>>>(w, wsq);
    emc_demod_kernel<<<32, 256, 0, stream>>>(s_, wsq, d_);
    emc_wrepack_kernel<<<9216, 256, 0, stream>>>(w, wb);
    emc_conv_kernel<<<16 * 62, 512, 0, stream>>>(x, wb, s_, d_, out);
}